// Round 3
// baseline (848.146 us; speedup 1.0000x reference)
//
#include <hip/hip_runtime.h>
#include <hip/hip_bf16.h>

#define D_MODEL 1024
#define D_FF    4096
#define N_EXPERTS 8
#define TOPK    2
#define T_TOK   4096
#define NPAIR   (T_TOK * TOPK)   // 8192
#define MT_MAX  32               // ceil(T_TOK / 128)
#define KSPLIT  2                // gemm2 split-K

typedef __attribute__((ext_vector_type(8))) short s8v;          // bf16x8 MFMA frag
typedef __attribute__((ext_vector_type(4))) float f4v;          // fp32x4 MFMA acc
typedef __attribute__((ext_vector_type(8))) unsigned short u16x8;

__device__ __forceinline__ void async16(const void* g, void* l) {
    __builtin_amdgcn_global_load_lds(
        (const __attribute__((address_space(1))) void*)g,
        (__attribute__((address_space(3))) void*)l, 16, 0, 0);
}

__device__ __forceinline__ float gelu_tanh(float v) {
    float u = 0.7978845608028654f * (v + 0.044715f * v * v * v);
    float t = 1.0f - 2.0f / (1.0f + __expf(2.0f * u));
    return 0.5f * v * (1.0f + t);
}

__device__ __forceinline__ unsigned short f2bf(float f) {
    union { __hip_bfloat16 b; unsigned short u; } cv;
    cv.b = __float2bfloat16(f);
    return cv.u;
}

// ---------------------------------------------------------------- router
__global__ __launch_bounds__(256) void router_kernel(
    const float* __restrict__ x, const float* __restrict__ Wg,
    int* __restrict__ top_e, float* __restrict__ top_w,
    int* __restrict__ counts)
{
    int wave = threadIdx.x >> 6;
    int lane = threadIdx.x & 63;
    int t = blockIdx.x * 4 + wave;
    if (t >= T_TOK) return;

    float acc[8] = {0.f,0.f,0.f,0.f,0.f,0.f,0.f,0.f};
    const float* xr = x + (size_t)t * D_MODEL;
    for (int d = lane; d < D_MODEL; d += 64) {
        float xv = xr[d];
        const float* wr = Wg + d * N_EXPERTS;
        float4 w0 = *(const float4*)wr;
        float4 w1 = *(const float4*)(wr + 4);
        acc[0] += xv * w0.x; acc[1] += xv * w0.y;
        acc[2] += xv * w0.z; acc[3] += xv * w0.w;
        acc[4] += xv * w1.x; acc[5] += xv * w1.y;
        acc[6] += xv * w1.z; acc[7] += xv * w1.w;
    }
    #pragma unroll
    for (int off = 32; off >= 1; off >>= 1) {
        #pragma unroll
        for (int e = 0; e < 8; e++) acc[e] += __shfl_xor(acc[e], off);
    }
    if (lane == 0) {
        float m = acc[0];
        #pragma unroll
        for (int e = 1; e < 8; e++) m = fmaxf(m, acc[e]);
        float p[8]; float s = 0.f;
        #pragma unroll
        for (int e = 0; e < 8; e++) { p[e] = expf(acc[e] - m); s += p[e]; }
        float inv = 1.f / s;
        #pragma unroll
        for (int e = 0; e < 8; e++) p[e] *= inv;
        int i0 = 0; float b0 = p[0];
        #pragma unroll
        for (int e = 1; e < 8; e++) if (p[e] > b0) { b0 = p[e]; i0 = e; }
        int i1 = -1; float b1 = -1.f;
        #pragma unroll
        for (int e = 0; e < 8; e++) if (e != i0 && p[e] > b1) { b1 = p[e]; i1 = e; }
        top_e[2*t]   = i0; top_w[2*t]   = b0;
        top_e[2*t+1] = i1; top_w[2*t+1] = b1;
        atomicAdd(&counts[i0], 1);
        atomicAdd(&counts[i1], 1);
    }
}

// ---------------------------------------------------------------- offsets
__global__ void offsets_kernel(const int* __restrict__ counts, int* __restrict__ offsets)
{
    if (threadIdx.x == 0 && blockIdx.x == 0) {
        int run = 0;
        for (int e = 0; e < N_EXPERTS; e++) { offsets[e] = run; run += counts[e]; }
        offsets[N_EXPERTS] = run;
    }
}

// ---------------------------------------------------------------- scatter
__global__ __launch_bounds__(256) void scatter_kernel(
    const int* __restrict__ top_e, const int* __restrict__ offsets,
    int* __restrict__ counts2, int* __restrict__ pair_id)
{
    int t = blockIdx.x * blockDim.x + threadIdx.x;
    if (t >= T_TOK) return;
    #pragma unroll
    for (int k = 0; k < TOPK; k++) {
        int e = top_e[2*t + k];
        int pos = atomicAdd(&counts2[e], 1);
        pair_id[offsets[e] + pos] = 2*t + k;
    }
}

// ---------------------------------------------------------------- cast x -> bf16
__global__ __launch_bounds__(256) void cast_x_kernel(
    const float* __restrict__ x, __hip_bfloat16* __restrict__ xb)
{
    int i = (blockIdx.x * 256 + threadIdx.x) * 8;
    float4 a = *(const float4*)(x + i);
    float4 b = *(const float4*)(x + i + 4);
    unsigned short t[8];
    t[0]=f2bf(a.x); t[1]=f2bf(a.y); t[2]=f2bf(a.z); t[3]=f2bf(a.w);
    t[4]=f2bf(b.x); t[5]=f2bf(b.y); t[6]=f2bf(b.z); t[7]=f2bf(b.w);
    *(u16x8*)((unsigned short*)xb + i) = *(u16x8*)t;
}

// ------------------------------------------------- transpose-cast W -> [E][N][K] bf16
__global__ __launch_bounds__(256) void transpose_cast_kernel(
    const float* __restrict__ src, __hip_bfloat16* __restrict__ dst, int R, int C)
{
    int e = blockIdx.z;
    src += (size_t)e * R * C;
    dst += (size_t)e * R * C;
    int b0 = blockIdx.x * 64;
    int a0 = blockIdx.y * 64;

    __shared__ float tile[64][65];
    int tid = threadIdx.x;
    int lr = tid >> 4;
    int lc = (tid & 15) * 4;
    #pragma unroll
    for (int rr = 0; rr < 4; rr++) {
        int r = lr + rr * 16;
        *(float4*)&tile[r][lc] = *(const float4*)(src + (size_t)(a0 + r) * C + b0 + lc);
    }
    __syncthreads();
    int oc = tid >> 3;
    int oj = (tid & 7) * 8;
    #pragma unroll
    for (int rr = 0; rr < 2; rr++) {
        int c = oc + rr * 32;
        unsigned short t[8];
        #pragma unroll
        for (int j = 0; j < 8; j++) t[j] = f2bf(tile[oj + j][c]);
        *(u16x8*)((unsigned short*)dst + (size_t)(b0 + c) * R + a0 + oj) = *(u16x8*)t;
    }
}

// ---------------------------------------------------------------- GEMM1 (MFMA)
// LDS layout (MFMA-direct, conflict-free): chunk c (16B) of As/Bs holds
// global row rb*16+fm, k-chunk kb where rb=c>>6, kb=(c>>4)&3, fm=c&15.
// Fragment read for region rb is then As + rb*512 + lane*8 (lane-linear).
__global__ __launch_bounds__(256) void gemm1_mfma(
    const __hip_bfloat16* __restrict__ xb, const __hip_bfloat16* __restrict__ W1T,
    const float* __restrict__ b1,
    const int* __restrict__ offsets, const int* __restrict__ pair_id,
    __hip_bfloat16* __restrict__ h)
{
    int e  = blockIdx.y >> 5;
    int mt = blockIdx.y & 31;
    int off_e = offsets[e];
    int cnt   = offsets[e + 1] - off_e;
    int m0 = mt * 128;
    if (m0 >= cnt) return;
    int n0 = blockIdx.x * 128;

    __shared__ __hip_bfloat16 As[128 * 32];
    __shared__ __hip_bfloat16 Bs[128 * 32];
    __shared__ int pid[128];

    int tid = threadIdx.x;
    if (tid < 128) {
        int r = m0 + tid; if (r >= cnt) r = cnt - 1;
        pid[tid] = pair_id[off_e + r];
    }
    __syncthreads();

    int lane = tid & 63, wid = tid >> 6;
    int c0 = tid, c1 = tid + 256;
    int r0 = ((c0 >> 6) << 4) | (c0 & 15), kb0 = (c0 >> 4) & 3;
    int r1 = ((c1 >> 6) << 4) | (c1 & 15), kb1 = (c1 >> 4) & 3;

    const __hip_bfloat16* gA0 = xb + (size_t)(pid[r0] >> 1) * D_MODEL + kb0 * 8;
    const __hip_bfloat16* gA1 = xb + (size_t)(pid[r1] >> 1) * D_MODEL + kb1 * 8;
    const __hip_bfloat16* WT  = W1T + (size_t)e * (D_MODEL * D_FF);
    const __hip_bfloat16* gB0 = WT + (size_t)(n0 + r0) * D_MODEL + kb0 * 8;
    const __hip_bfloat16* gB1 = WT + (size_t)(n0 + r1) * D_MODEL + kb1 * 8;

    int fm = lane & 15;
    int wm = (wid >> 1) * 64;
    int wn = (wid & 1) * 64;
    int rba = (wid >> 1) * 4;     // A region base (row blocks of 16)
    int rbb = (wid & 1) * 4;      // B region base

    f4v acc[4][4];
    #pragma unroll
    for (int i = 0; i < 4; i++)
        #pragma unroll
        for (int j = 0; j < 4; j++)
            acc[i][j] = (f4v){0.f, 0.f, 0.f, 0.f};

    for (int k0 = 0; k0 < D_MODEL; k0 += 32) {
        async16(gA0 + k0, As + c0 * 8);
        async16(gA1 + k0, As + c1 * 8);
        async16(gB0 + k0, Bs + c0 * 8);
        async16(gB1 + k0, Bs + c1 * 8);
        __syncthreads();
        s8v af[4], bfr[4];
        #pragma unroll
        for (int i = 0; i < 4; i++)
            af[i] = *(const s8v*)(As + (rba + i) * 512 + lane * 8);
        #pragma unroll
        for (int j = 0; j < 4; j++)
            bfr[j] = *(const s8v*)(Bs + (rbb + j) * 512 + lane * 8);
        #pragma unroll
        for (int i = 0; i < 4; i++)
            #pragma unroll
            for (int j = 0; j < 4; j++)
                acc[i][j] = __builtin_amdgcn_mfma_f32_16x16x32_bf16(af[i], bfr[j], acc[i][j], 0, 0, 0);
        __syncthreads();
    }

    int rq = (lane >> 4) * 4;   // C/D: row = (lane>>4)*4 + reg, col = lane&15
    #pragma unroll
    for (int i = 0; i < 4; i++) {
        #pragma unroll
        for (int j = 0; j < 4; j++) {
            int n = n0 + wn + j * 16 + fm;
            float bias = b1[e * D_FF + n];
            #pragma unroll
            for (int r = 0; r < 4; r++) {
                int m = wm + i * 16 + rq + r;
                if (m0 + m < cnt) {
                    float v = acc[i][j][r] + bias;
                    h[(size_t)(off_e + m0 + m) * D_FF + n] = __float2bfloat16(gelu_tanh(v));
                }
            }
        }
    }
}

// ---------------------------------------------------------------- GEMM2 (MFMA, split-K)
__global__ __launch_bounds__(256) void gemm2_mfma(
    const __hip_bfloat16* __restrict__ h, const __hip_bfloat16* __restrict__ W2T,
    const float* __restrict__ b2,
    const int* __restrict__ offsets, const int* __restrict__ pair_id,
    float* __restrict__ yp)
{
    int bz = blockIdx.y;          // ((e*32 + mt)*KSPLIT + s)
    int s  = bz & (KSPLIT - 1);
    int mt = (bz / KSPLIT) & 31;
    int e  = bz / (KSPLIT * 32);
    int off_e = offsets[e];
    int cnt   = offsets[e + 1] - off_e;
    int m0 = mt * 128;
    if (m0 >= cnt) return;
    int n0 = blockIdx.x * 128;
    int kbeg = s * (D_FF / KSPLIT);
    int kend = kbeg + D_FF / KSPLIT;

    __shared__ __hip_bfloat16 As[128 * 32];
    __shared__ __hip_bfloat16 Bs[128 * 32];
    __shared__ int pid[128];

    int tid = threadIdx.x;
    if (tid < 128) {
        int r = m0 + tid; if (r >= cnt) r = cnt - 1;
        pid[tid] = pair_id[off_e + r];
    }
    __syncthreads();

    int lane = tid & 63, wid = tid >> 6;
    int c0 = tid, c1 = tid + 256;
    int r0 = ((c0 >> 6) << 4) | (c0 & 15), kb0 = (c0 >> 4) & 3;
    int r1 = ((c1 >> 6) << 4) | (c1 & 15), kb1 = (c1 >> 4) & 3;
    int mr0 = m0 + r0; if (mr0 >= cnt) mr0 = cnt - 1;
    int mr1 = m0 + r1; if (mr1 >= cnt) mr1 = cnt - 1;

    const __hip_bfloat16* gA0 = h + (size_t)(off_e + mr0) * D_FF + kb0 * 8;
    const __hip_bfloat16* gA1 = h + (size_t)(off_e + mr1) * D_FF + kb1 * 8;
    const __hip_bfloat16* WT  = W2T + (size_t)e * (D_FF * D_MODEL);
    const __hip_bfloat16* gB0 = WT + (size_t)(n0 + r0) * D_FF + kb0 * 8;
    const __hip_bfloat16* gB1 = WT + (size_t)(n0 + r1) * D_FF + kb1 * 8;

    int fm = lane & 15;
    int wm = (wid >> 1) * 64;
    int wn = (wid & 1) * 64;
    int rba = (wid >> 1) * 4;
    int rbb = (wid & 1) * 4;

    f4v acc[4][4];
    #pragma unroll
    for (int i = 0; i < 4; i++)
        #pragma unroll
        for (int j = 0; j < 4; j++)
            acc[i][j] = (f4v){0.f, 0.f, 0.f, 0.f};

    for (int k0 = kbeg; k0 < kend; k0 += 32) {
        async16(gA0 + k0, As + c0 * 8);
        async16(gA1 + k0, As + c1 * 8);
        async16(gB0 + k0, Bs + c0 * 8);
        async16(gB1 + k0, Bs + c1 * 8);
        __syncthreads();
        s8v af[4], bfr[4];
        #pragma unroll
        for (int i = 0; i < 4; i++)
            af[i] = *(const s8v*)(As + (rba + i) * 512 + lane * 8);
        #pragma unroll
        for (int j = 0; j < 4; j++)
            bfr[j] = *(const s8v*)(Bs + (rbb + j) * 512 + lane * 8);
        #pragma unroll
        for (int i = 0; i < 4; i++)
            #pragma unroll
            for (int j = 0; j < 4; j++)
                acc[i][j] = __builtin_amdgcn_mfma_f32_16x16x32_bf16(af[i], bfr[j], acc[i][j], 0, 0, 0);
        __syncthreads();
    }

    float* yout = yp + (size_t)s * NPAIR * D_MODEL;
    int rq = (lane >> 4) * 4;
    #pragma unroll
    for (int i = 0; i < 4; i++) {
        #pragma unroll
        for (int j = 0; j < 4; j++) {
            int n = n0 + wn + j * 16 + fm;
            float bias = (s == 0) ? b2[e * D_MODEL + n] : 0.f;
            #pragma unroll
            for (int r = 0; r < 4; r++) {
                int m = wm + i * 16 + rq + r;
                if (m0 + m < cnt) {
                    int p = pid[m];
                    yout[(size_t)p * D_MODEL + n] = acc[i][j][r] + bias;
                }
            }
        }
    }
}

// ---------------------------------------------------------------- combine (sums splits)
__global__ __launch_bounds__(256) void combine_kernel(
    const float* __restrict__ yp, const float* __restrict__ top_w,
    float* __restrict__ out)
{
    int gid = blockIdx.x * blockDim.x + threadIdx.x;
    int t = gid >> 8;
    int c = gid & 255;
    float w0 = top_w[2*t];
    float w1 = top_w[2*t + 1];
    const float4* y0a = (const float4*)(yp + (size_t)(2*t) * D_MODEL);
    const float4* y1a = (const float4*)(yp + (size_t)(2*t + 1) * D_MODEL);
    const float4* y0b = (const float4*)(yp + (size_t)NPAIR * D_MODEL + (size_t)(2*t) * D_MODEL);
    const float4* y1b = (const float4*)(yp + (size_t)NPAIR * D_MODEL + (size_t)(2*t + 1) * D_MODEL);
    float4 a0 = y0a[c], a1 = y0b[c];
    float4 b0 = y1a[c], b1 = y1b[c];
    float4 o;
    o.x = w0*(a0.x+a1.x) + w1*(b0.x+b1.x);
    o.y = w0*(a0.y+a1.y) + w1*(b0.y+b1.y);
    o.z = w0*(a0.z+a1.z) + w1*(b0.z+b1.z);
    o.w = w0*(a0.w+a1.w) + w1*(b0.w+b1.w);
    ((float4*)out)[gid] = o;
}

// ---------------------------------------------------------------- launch
extern "C" void kernel_launch(void* const* d_in, const int* in_sizes, int n_in,
                              void* d_out, int out_size, void* d_ws, size_t ws_size,
                              hipStream_t stream)
{
    const float* x  = (const float*)d_in[0];
    const float* Wg = (const float*)d_in[1];
    const float* W1 = (const float*)d_in[2];
    const float* b1 = (const float*)d_in[3];
    const float* W2 = (const float*)d_in[4];
    const float* b2 = (const float*)d_in[5];
    float* out = (float*)d_out;

    char* ws = (char*)d_ws;
    size_t off = 0;
    int*   top_e   = (int*)(ws + off);  off += (size_t)NPAIR * 4;
    float* top_w   = (float*)(ws + off); off += (size_t)NPAIR * 4;
    int*   counts  = (int*)(ws + off);
    int*   counts2 = counts + N_EXPERTS;
    int*   offsets = counts2 + N_EXPERTS; off += 256;
    int*   pair_id = (int*)(ws + off);  off += (size_t)NPAIR * 4;
    off = (off + 255) & ~(size_t)255;
    __hip_bfloat16* xb  = (__hip_bfloat16*)(ws + off); off += (size_t)T_TOK * D_MODEL * 2;
    __hip_bfloat16* W1T = (__hip_bfloat16*)(ws + off); off += (size_t)N_EXPERTS * D_MODEL * D_FF * 2;
    __hip_bfloat16* W2T = (__hip_bfloat16*)(ws + off); off += (size_t)N_EXPERTS * D_MODEL * D_FF * 2;
    __hip_bfloat16* h   = (__hip_bfloat16*)(ws + off); off += (size_t)NPAIR * D_FF * 2;
    float*          yp  = (float*)(ws + off);          off += (size_t)KSPLIT * NPAIR * D_MODEL * 4;

    hipMemsetAsync(counts, 0, 256, stream);

    router_kernel<<<T_TOK / 4, 256, 0, stream>>>(x, Wg, top_e, top_w, counts);
    offsets_kernel<<<1, 64, 0, stream>>>(counts, offsets);
    scatter_kernel<<<T_TOK / 256, 256, 0, stream>>>(top_e, offsets, counts2, pair_id);

    cast_x_kernel<<<(T_TOK * D_MODEL) / (256 * 8), 256, 0, stream>>>(x, xb);
    transpose_cast_kernel<<<dim3(D_FF / 64, D_MODEL / 64, N_EXPERTS), 256, 0, stream>>>(
        W1, W1T, D_MODEL, D_FF);
    transpose_cast_kernel<<<dim3(D_MODEL / 64, D_FF / 64, N_EXPERTS), 256, 0, stream>>>(
        W2, W2T, D_FF, D_MODEL);

    gemm1_mfma<<<dim3(D_FF / 128, N_EXPERTS * MT_MAX), 256, 0, stream>>>(
        xb, W1T, b1, offsets, pair_id, h);
    gemm2_mfma<<<dim3(D_MODEL / 128, N_EXPERTS * MT_MAX * KSPLIT), 256, 0, stream>>>(
        h, W2T, b2, offsets, pair_id, yp);
    combine_kernel<<<T_TOK, 256, 0, stream>>>(yp, top_w, out);
}

// Round 4
// 717.886 us; speedup vs baseline: 1.1815x; 1.1815x over previous
//
#include <hip/hip_runtime.h>
#include <hip/hip_bf16.h>

#define D_MODEL 1024
#define D_FF    4096
#define N_EXPERTS 8
#define TOPK    2
#define T_TOK   4096
#define NPAIR   (T_TOK * TOPK)   // 8192
#define MT_MAX  32               // ceil(T_TOK / 128)

typedef __attribute__((ext_vector_type(8))) short s8v;          // bf16x8 MFMA frag
typedef __attribute__((ext_vector_type(4))) float f4v;          // fp32x4 MFMA acc
typedef __attribute__((ext_vector_type(4))) unsigned short u16x4;
typedef __attribute__((ext_vector_type(8))) unsigned short u16x8;

__device__ __forceinline__ void async16(const void* g, void* l) {
    __builtin_amdgcn_global_load_lds(
        (const __attribute__((address_space(1))) void*)g,
        (__attribute__((address_space(3))) void*)l, 16, 0, 0);
}

__device__ __forceinline__ float gelu_tanh(float v) {
    float u = 0.7978845608028654f * (v + 0.044715f * v * v * v);
    float t = 1.0f - 2.0f / (1.0f + __expf(2.0f * u));
    return 0.5f * v * (1.0f + t);
}

__device__ __forceinline__ unsigned short f2bf(float f) {
    union { __hip_bfloat16 b; unsigned short u; } cv;
    cv.b = __float2bfloat16(f);
    return cv.u;
}

// ---------------------------------------------------------------- router (+x cast)
// one wave per token: logits over 8 experts (fp32 for exact top-k), softmax, top-2.
// Also writes the bf16 copy of the x row (fused cast_x).
__global__ __launch_bounds__(256) void router_kernel(
    const float* __restrict__ x, const float* __restrict__ Wg,
    int* __restrict__ top_e, float* __restrict__ top_w,
    __hip_bfloat16* __restrict__ xb)
{
    int wave = threadIdx.x >> 6;
    int lane = threadIdx.x & 63;
    int t = blockIdx.x * 4 + wave;
    if (t >= T_TOK) return;

    float acc[8] = {0.f,0.f,0.f,0.f,0.f,0.f,0.f,0.f};
    const float* xr = x + (size_t)t * D_MODEL;
    unsigned short* xbr = (unsigned short*)xb + (size_t)t * D_MODEL;
    #pragma unroll
    for (int it = 0; it < 4; it++) {
        int d0 = it * 256 + lane * 4;
        float4 xv = *(const float4*)(xr + d0);
        unsigned short bfv[4] = {f2bf(xv.x), f2bf(xv.y), f2bf(xv.z), f2bf(xv.w)};
        *(u16x4*)(xbr + d0) = *(u16x4*)bfv;
        float xa[4] = {xv.x, xv.y, xv.z, xv.w};
        #pragma unroll
        for (int u = 0; u < 4; u++) {
            const float* wr = Wg + (size_t)(d0 + u) * N_EXPERTS;
            float4 w0 = *(const float4*)wr;
            float4 w1 = *(const float4*)(wr + 4);
            acc[0] += xa[u] * w0.x; acc[1] += xa[u] * w0.y;
            acc[2] += xa[u] * w0.z; acc[3] += xa[u] * w0.w;
            acc[4] += xa[u] * w1.x; acc[5] += xa[u] * w1.y;
            acc[6] += xa[u] * w1.z; acc[7] += xa[u] * w1.w;
        }
    }
    #pragma unroll
    for (int off = 32; off >= 1; off >>= 1) {
        #pragma unroll
        for (int e = 0; e < 8; e++) acc[e] += __shfl_xor(acc[e], off);
    }
    if (lane == 0) {
        float m = acc[0];
        #pragma unroll
        for (int e = 1; e < 8; e++) m = fmaxf(m, acc[e]);
        float p[8]; float s = 0.f;
        #pragma unroll
        for (int e = 0; e < 8; e++) { p[e] = expf(acc[e] - m); s += p[e]; }
        float inv = 1.f / s;
        #pragma unroll
        for (int e = 0; e < 8; e++) p[e] *= inv;
        int i0 = 0; float b0 = p[0];
        #pragma unroll
        for (int e = 1; e < 8; e++) if (p[e] > b0) { b0 = p[e]; i0 = e; }
        int i1 = -1; float b1 = -1.f;
        #pragma unroll
        for (int e = 0; e < 8; e++) if (e != i0 && p[e] > b1) { b1 = p[e]; i1 = e; }
        top_e[2*t]   = i0; top_w[2*t]   = b0;
        top_e[2*t+1] = i1; top_w[2*t+1] = b1;
    }
}

// ------------------------------------------- setup: histogram + offsets + scatter
// single block; replaces memset + offsets + scatter kernels
__global__ __launch_bounds__(256) void setup_kernel(
    const int* __restrict__ top_e, int* __restrict__ offsets,
    int* __restrict__ pair_id)
{
    __shared__ int cnt[N_EXPERTS], base[N_EXPERTS], cur[N_EXPERTS];
    int tid = threadIdx.x;
    if (tid < N_EXPERTS) { cnt[tid] = 0; cur[tid] = 0; }
    __syncthreads();
    for (int i = tid; i < NPAIR; i += 256) atomicAdd(&cnt[top_e[i]], 1);
    __syncthreads();
    if (tid == 0) {
        int run = 0;
        #pragma unroll
        for (int e = 0; e < N_EXPERTS; e++) { base[e] = run; offsets[e] = run; run += cnt[e]; }
        offsets[N_EXPERTS] = run;
    }
    __syncthreads();
    for (int i = tid; i < NPAIR; i += 256) {
        int e = top_e[i];
        int pos = atomicAdd(&cur[e], 1);
        pair_id[base[e] + pos] = i;
    }
}

// ------------------------------------------------- transpose-cast W -> [E][N][K] bf16
__global__ __launch_bounds__(256) void transpose_cast_kernel(
    const float* __restrict__ src, __hip_bfloat16* __restrict__ dst, int R, int C)
{
    int e = blockIdx.z;
    src += (size_t)e * R * C;
    dst += (size_t)e * R * C;
    int b0 = blockIdx.x * 64;
    int a0 = blockIdx.y * 64;

    __shared__ float tile[64][65];
    int tid = threadIdx.x;
    int lr = tid >> 4;
    int lc = (tid & 15) * 4;
    #pragma unroll
    for (int rr = 0; rr < 4; rr++) {
        int r = lr + rr * 16;
        *(float4*)&tile[r][lc] = *(const float4*)(src + (size_t)(a0 + r) * C + b0 + lc);
    }
    __syncthreads();
    int oc = tid >> 3;
    int oj = (tid & 7) * 8;
    #pragma unroll
    for (int rr = 0; rr < 2; rr++) {
        int c = oc + rr * 32;
        unsigned short t[8];
        #pragma unroll
        for (int j = 0; j < 8; j++) t[j] = f2bf(tile[oj + j][c]);
        *(u16x8*)((unsigned short*)dst + (size_t)(b0 + c) * R + a0 + oj) = *(u16x8*)t;
    }
}

// ---------------------------------------------------------------- GEMM1 (MFMA)
// LDS layout (MFMA-direct, conflict-free): chunk c (16B) of As/Bs holds
// global row rb*16+fm, k-chunk kb where rb=c>>6, kb=(c>>4)&3, fm=c&15.
// Fragment read for region rb is then As + rb*512 + lane*8 (lane-linear).
__global__ __launch_bounds__(256) void gemm1_mfma(
    const __hip_bfloat16* __restrict__ xb, const __hip_bfloat16* __restrict__ W1T,
    const float* __restrict__ b1,
    const int* __restrict__ offsets, const int* __restrict__ pair_id,
    __hip_bfloat16* __restrict__ h)
{
    int e  = blockIdx.y >> 5;
    int mt = blockIdx.y & 31;
    int off_e = offsets[e];
    int cnt   = offsets[e + 1] - off_e;
    int m0 = mt * 128;
    if (m0 >= cnt) return;
    int n0 = blockIdx.x * 128;

    __shared__ __hip_bfloat16 As[128 * 32];
    __shared__ __hip_bfloat16 Bs[128 * 32];
    __shared__ int pid[128];

    int tid = threadIdx.x;
    if (tid < 128) {
        int r = m0 + tid; if (r >= cnt) r = cnt - 1;
        pid[tid] = pair_id[off_e + r];
    }
    __syncthreads();

    int lane = tid & 63, wid = tid >> 6;
    int c0 = tid, c1 = tid + 256;
    int r0 = ((c0 >> 6) << 4) | (c0 & 15), kb0 = (c0 >> 4) & 3;
    int r1 = ((c1 >> 6) << 4) | (c1 & 15), kb1 = (c1 >> 4) & 3;

    const __hip_bfloat16* gA0 = xb + (size_t)(pid[r0] >> 1) * D_MODEL + kb0 * 8;
    const __hip_bfloat16* gA1 = xb + (size_t)(pid[r1] >> 1) * D_MODEL + kb1 * 8;
    const __hip_bfloat16* WT  = W1T + (size_t)e * (D_MODEL * D_FF);
    const __hip_bfloat16* gB0 = WT + (size_t)(n0 + r0) * D_MODEL + kb0 * 8;
    const __hip_bfloat16* gB1 = WT + (size_t)(n0 + r1) * D_MODEL + kb1 * 8;

    int fm = lane & 15;
    int wm = (wid >> 1) * 64;
    int wn = (wid & 1) * 64;
    int rba = (wid >> 1) * 4;     // A region base (row blocks of 16)
    int rbb = (wid & 1) * 4;      // B region base

    f4v acc[4][4];
    #pragma unroll
    for (int i = 0; i < 4; i++)
        #pragma unroll
        for (int j = 0; j < 4; j++)
            acc[i][j] = (f4v){0.f, 0.f, 0.f, 0.f};

    for (int k0 = 0; k0 < D_MODEL; k0 += 32) {
        async16(gA0 + k0, As + c0 * 8);
        async16(gA1 + k0, As + c1 * 8);
        async16(gB0 + k0, Bs + c0 * 8);
        async16(gB1 + k0, Bs + c1 * 8);
        __syncthreads();
        s8v af[4], bfr[4];
        #pragma unroll
        for (int i = 0; i < 4; i++)
            af[i] = *(const s8v*)(As + (rba + i) * 512 + lane * 8);
        #pragma unroll
        for (int j = 0; j < 4; j++)
            bfr[j] = *(const s8v*)(Bs + (rbb + j) * 512 + lane * 8);
        #pragma unroll
        for (int i = 0; i < 4; i++)
            #pragma unroll
            for (int j = 0; j < 4; j++)
                acc[i][j] = __builtin_amdgcn_mfma_f32_16x16x32_bf16(af[i], bfr[j], acc[i][j], 0, 0, 0);
        __syncthreads();
    }

    int rq = (lane >> 4) * 4;   // C/D: row = (lane>>4)*4 + reg, col = lane&15
    #pragma unroll
    for (int i = 0; i < 4; i++) {
        #pragma unroll
        for (int j = 0; j < 4; j++) {
            int n = n0 + wn + j * 16 + fm;
            float bias = b1[e * D_FF + n];
            #pragma unroll
            for (int r = 0; r < 4; r++) {
                int m = wm + i * 16 + rq + r;
                if (m0 + m < cnt) {
                    float v = acc[i][j][r] + bias;
                    h[(size_t)(off_e + m0 + m) * D_FF + n] = __float2bfloat16(gelu_tanh(v));
                }
            }
        }
    }
}

// ---------------------------------------------------------------- GEMM2 (MFMA)
__global__ __launch_bounds__(256) void gemm2_mfma(
    const __hip_bfloat16* __restrict__ h, const __hip_bfloat16* __restrict__ W2T,
    const float* __restrict__ b2,
    const int* __restrict__ offsets, const int* __restrict__ pair_id,
    float* __restrict__ y)
{
    int e  = blockIdx.y >> 5;
    int mt = blockIdx.y & 31;
    int off_e = offsets[e];
    int cnt   = offsets[e + 1] - off_e;
    int m0 = mt * 128;
    if (m0 >= cnt) return;
    int n0 = blockIdx.x * 128;

    __shared__ __hip_bfloat16 As[128 * 32];
    __shared__ __hip_bfloat16 Bs[128 * 32];
    __shared__ int pid[128];

    int tid = threadIdx.x;
    if (tid < 128) {
        int r = m0 + tid; if (r >= cnt) r = cnt - 1;
        pid[tid] = pair_id[off_e + r];
    }
    __syncthreads();

    int lane = tid & 63, wid = tid >> 6;
    int c0 = tid, c1 = tid + 256;
    int r0 = ((c0 >> 6) << 4) | (c0 & 15), kb0 = (c0 >> 4) & 3;
    int r1 = ((c1 >> 6) << 4) | (c1 & 15), kb1 = (c1 >> 4) & 3;
    int mr0 = m0 + r0; if (mr0 >= cnt) mr0 = cnt - 1;
    int mr1 = m0 + r1; if (mr1 >= cnt) mr1 = cnt - 1;

    const __hip_bfloat16* gA0 = h + (size_t)(off_e + mr0) * D_FF + kb0 * 8;
    const __hip_bfloat16* gA1 = h + (size_t)(off_e + mr1) * D_FF + kb1 * 8;
    const __hip_bfloat16* WT  = W2T + (size_t)e * (D_FF * D_MODEL);
    const __hip_bfloat16* gB0 = WT + (size_t)(n0 + r0) * D_FF + kb0 * 8;
    const __hip_bfloat16* gB1 = WT + (size_t)(n0 + r1) * D_FF + kb1 * 8;

    int fm = lane & 15;
    int wm = (wid >> 1) * 64;
    int wn = (wid & 1) * 64;
    int rba = (wid >> 1) * 4;
    int rbb = (wid & 1) * 4;

    f4v acc[4][4];
    #pragma unroll
    for (int i = 0; i < 4; i++)
        #pragma unroll
        for (int j = 0; j < 4; j++)
            acc[i][j] = (f4v){0.f, 0.f, 0.f, 0.f};

    for (int k0 = 0; k0 < D_FF; k0 += 32) {
        async16(gA0 + k0, As + c0 * 8);
        async16(gA1 + k0, As + c1 * 8);
        async16(gB0 + k0, Bs + c0 * 8);
        async16(gB1 + k0, Bs + c1 * 8);
        __syncthreads();
        s8v af[4], bfr[4];
        #pragma unroll
        for (int i = 0; i < 4; i++)
            af[i] = *(const s8v*)(As + (rba + i) * 512 + lane * 8);
        #pragma unroll
        for (int j = 0; j < 4; j++)
            bfr[j] = *(const s8v*)(Bs + (rbb + j) * 512 + lane * 8);
        #pragma unroll
        for (int i = 0; i < 4; i++)
            #pragma unroll
            for (int j = 0; j < 4; j++)
                acc[i][j] = __builtin_amdgcn_mfma_f32_16x16x32_bf16(af[i], bfr[j], acc[i][j], 0, 0, 0);
        __syncthreads();
    }

    int rq = (lane >> 4) * 4;
    #pragma unroll
    for (int i = 0; i < 4; i++) {
        #pragma unroll
        for (int j = 0; j < 4; j++) {
            int n = n0 + wn + j * 16 + fm;
            float bias = b2[e * D_MODEL + n];
            #pragma unroll
            for (int r = 0; r < 4; r++) {
                int m = wm + i * 16 + rq + r;
                if (m0 + m < cnt) {
                    int p = pid[m];
                    y[(size_t)p * D_MODEL + n] = acc[i][j][r] + bias;
                }
            }
        }
    }
}

// ---------------------------------------------------------------- combine
__global__ __launch_bounds__(256) void combine_kernel(
    const float* __restrict__ y, const float* __restrict__ top_w,
    float* __restrict__ out)
{
    int gid = blockIdx.x * blockDim.x + threadIdx.x;
    int t = gid >> 8;
    int c = gid & 255;
    float w0 = top_w[2*t];
    float w1 = top_w[2*t + 1];
    const float4* y0 = (const float4*)(y + (size_t)(2*t) * D_MODEL);
    const float4* y1 = (const float4*)(y + (size_t)(2*t + 1) * D_MODEL);
    float4 a = y0[c], b = y1[c];
    float4 o;
    o.x = w0*a.x + w1*b.x; o.y = w0*a.y + w1*b.y;
    o.z = w0*a.z + w1*b.z; o.w = w0*a.w + w1*b.w;
    ((float4*)out)[gid] = o;
}

// ---------------------------------------------------------------- launch
extern "C" void kernel_launch(void* const* d_in, const int* in_sizes, int n_in,
                              void* d_out, int out_size, void* d_ws, size_t ws_size,
                              hipStream_t stream)
{
    const float* x  = (const float*)d_in[0];
    const float* Wg = (const float*)d_in[1];
    const float* W1 = (const float*)d_in[2];
    const float* b1 = (const float*)d_in[3];
    const float* W2 = (const float*)d_in[4];
    const float* b2 = (const float*)d_in[5];
    float* out = (float*)d_out;

    char* ws = (char*)d_ws;
    size_t off = 0;
    int*   top_e   = (int*)(ws + off);  off += (size_t)NPAIR * 4;
    float* top_w   = (float*)(ws + off); off += (size_t)NPAIR * 4;
    int*   offsets = (int*)(ws + off);  off += 256;
    int*   pair_id = (int*)(ws + off);  off += (size_t)NPAIR * 4;
    off = (off + 255) & ~(size_t)255;
    __hip_bfloat16* xb  = (__hip_bfloat16*)(ws + off); off += (size_t)T_TOK * D_MODEL * 2;
    __hip_bfloat16* W1T = (__hip_bfloat16*)(ws + off); off += (size_t)N_EXPERTS * D_MODEL * D_FF * 2;
    __hip_bfloat16* W2T = (__hip_bfloat16*)(ws + off); off += (size_t)N_EXPERTS * D_MODEL * D_FF * 2;
    __hip_bfloat16* h   = (__hip_bfloat16*)(ws + off); off += (size_t)NPAIR * D_FF * 2;
    float*          y   = (float*)(ws + off);          off += (size_t)NPAIR * D_MODEL * 4;

    router_kernel<<<T_TOK / 4, 256, 0, stream>>>(x, Wg, top_e, top_w, xb);
    setup_kernel<<<1, 256, 0, stream>>>(top_e, offsets, pair_id);

    transpose_cast_kernel<<<dim3(D_FF / 64, D_MODEL / 64, N_EXPERTS), 256, 0, stream>>>(
        W1, W1T, D_MODEL, D_FF);
    transpose_cast_kernel<<<dim3(D_MODEL / 64, D_FF / 64, N_EXPERTS), 256, 0, stream>>>(
        W2, W2T, D_FF, D_MODEL);

    gemm1_mfma<<<dim3(D_FF / 128, N_EXPERTS * MT_MAX), 256, 0, stream>>>(
        xb, W1T, b1, offsets, pair_id, h);
    gemm2_mfma<<<dim3(D_MODEL / 128, N_EXPERTS * MT_MAX), 256, 0, stream>>>(
        h, W2T, b2, offsets, pair_id, y);
    combine_kernel<<<T_TOK, 256, 0, stream>>>(y, top_w, out);
}